// Round 9
// baseline (404.989 us; speedup 1.0000x reference)
//
#include <hip/hip_runtime.h>
#include <hip/hip_bf16.h>

// ---------- constants ----------
#define T_TOK   100352      // 32 * 3136 tokens
#define NWIN    2048        // 32 * 64 windows
#define EPS_LN  1e-5f

typedef __attribute__((ext_vector_type(8))) short bf16x8;
typedef __attribute__((ext_vector_type(4))) float f32x4;

// ---------- helpers ----------
__device__ inline unsigned short f2bf(float f) {
  union { float f; unsigned int i; } c; c.f = f;
  unsigned int x = c.i;
  x += 0x7fffu + ((x >> 16) & 1u);   // round-to-nearest-even
  return (unsigned short)(x >> 16);
}
__device__ inline bf16x8 ld8(const unsigned short* p) {
  return *reinterpret_cast<const bf16x8*>(p);
}

// window-ordered row r (win*49 + n) -> token index (b*3136 + l)
__device__ inline int win_row_to_token(int r) {
  int win = r / 49, n = r % 49;
  int b  = win >> 6, w2 = win & 63;
  int wi = w2 >> 3,  wj = w2 & 7;
  int rr = n / 7,    cc = n % 7;
  return b * 3136 + (wi * 7 + rr) * 56 + (wj * 7 + cc);
}

// ---------- kernel 0: weights -> bf16, transposed to [N][K] ----------
__global__ void prep_weights(const float* __restrict__ qkv_w,
                             const float* __restrict__ proj_w,
                             const float* __restrict__ w1,
                             const float* __restrict__ w2,
                             unsigned short* __restrict__ wts) {
  int i = blockIdx.x * 256 + threadIdx.x;
  unsigned short* qkvt  = wts;            // [384][128]
  unsigned short* projt = wts + 49152;    // [128][128]
  unsigned short* w1t   = wts + 65536;    // [512][128]
  unsigned short* w2t   = wts + 131072;   // [128][512]
  if (i < 49152) {
    int n = i >> 7, k = i & 127; qkvt[i] = f2bf(qkv_w[k * 384 + n]);
  } else if (i < 65536) {
    int e = i - 49152; int n = e >> 7, k = e & 127; projt[e] = f2bf(proj_w[k * 128 + n]);
  } else if (i < 131072) {
    int e = i - 65536; int n = e >> 7, k = e & 127; w1t[e] = f2bf(w1[k * 512 + n]);
  } else if (i < 196608) {
    int e = i - 131072; int n = e >> 9, k = e & 511; w2t[e] = f2bf(w2[k * 128 + n]);
  }
}

// ---------- kernel 0b: bias+mask table in C-fragment order ----------
// cls2[cl][h][rt][ct][lane][reg] : 4*4*4*4*64*4 floats = 256 KB
__global__ void prep_cls(const float* __restrict__ rpb, float* __restrict__ cls2) {
  int i = blockIdx.x * 256 + threadIdx.x;          // 65536 total
  int reg = i & 3, lane = (i >> 2) & 63, ct = (i >> 8) & 3, rt = (i >> 10) & 3,
      h = (i >> 12) & 3, cl = (i >> 14) & 3;
  int n = rt * 16 + ((lane >> 4) << 2) + reg;
  int m = ct * 16 + (lane & 15);
  float v = -30000.f;                               // padding mask (finite, exp->0)
  if (n < 49 && m < 49) {
    int nr = n / 7, nc = n % 7, mr = m / 7, mc = m % 7;
    v = rpb[((nr - mr + 6) * 13 + (nc - mc + 6)) * 4 + h];
    int regn = ((cl & 2) ? (nr < 4 ? 3 : 6) : 0) + ((cl & 1) ? (nc < 4 ? 1 : 2) : 0);
    int regm = ((cl & 2) ? (mr < 4 ? 3 : 6) : 0) + ((cl & 1) ? (mc < 4 ? 1 : 2) : 0);
    if (regn != regm) v -= 100.f;
  }
  cls2[i] = v;
}

// ---------- layernorm (optionally gathering window-partition order) ----------
template<bool WINMAP>
__global__ __launch_bounds__(256) void ln_kernel(const float* __restrict__ x,
                                                 const float* __restrict__ w,
                                                 const float* __restrict__ b,
                                                 unsigned short* __restrict__ out) {
  int r    = blockIdx.x * 4 + (threadIdx.x >> 6);
  int lane = threadIdx.x & 63;
  int src  = WINMAP ? win_row_to_token(r) : r;
  float2 v = *reinterpret_cast<const float2*>(x + (long)src * 128 + lane * 2);
  float s  = v.x + v.y;
  float s2 = v.x * v.x + v.y * v.y;
#pragma unroll
  for (int off = 32; off; off >>= 1) {
    s  += __shfl_xor(s,  off);
    s2 += __shfl_xor(s2, off);
  }
  float mu  = s * (1.f / 128.f);
  float var = s2 * (1.f / 128.f) - mu * mu;
  float inv = rsqrtf(var + EPS_LN);
  int c = lane * 2;
  float2 wv = *reinterpret_cast<const float2*>(w + c);
  float2 bv = *reinterpret_cast<const float2*>(b + c);
  float y0 = (v.x - mu) * inv * wv.x + bv.x;
  float y1 = (v.y - mu) * inv * wv.y + bv.y;
  unsigned int pk = ((unsigned int)f2bf(y1) << 16) | (unsigned int)f2bf(y0);
  *reinterpret_cast<unsigned int*>(out + (long)r * 128 + c) = pk;
}

// ---------- 128x64-tile bf16 MFMA GEMM, XCD-swizzled 1-D grid ----------
// EPI 0: qkv -> bf16 out (stride 384) +bias
// EPI 1: proj -> f32 out1[t] = res[t] + acc + bias (window-reverse map)
template<int EPI, int KSTEPS, int NBN>
__global__ __launch_bounds__(256) void gemm_k(const unsigned short* __restrict__ A,
                                              const unsigned short* __restrict__ Wt,
                                              const float* __restrict__ bias,
                                              void* __restrict__ out,
                                              const float* __restrict__ res) {
  const int K = KSTEPS * 32;
  int flat  = blockIdx.x;
  int chunk = gridDim.x >> 3;
  int swz   = (flat & 7) * chunk + (flat >> 3);
  int ntile = swz % NBN, mpan = swz / NBN;

  int lane = threadIdx.x & 63;
  int wid  = threadIdx.x >> 6;
  int rowBase = mpan * 128 + wid * 32;
  int colBase = ntile * 64;
  int m  = lane & 15;
  int kg = lane >> 4;
  f32x4 acc[2][4] = {};
  const unsigned short* Ap = A  + (long)(rowBase + m) * K + kg * 8;
  const unsigned short* Bp = Wt + (long)(colBase + m) * K + kg * 8;
#pragma unroll 4
  for (int ks = 0; ks < KSTEPS; ks++) {
    bf16x8 b0 = ld8(Bp + 0 * 16 * K + ks * 32);
    bf16x8 b1 = ld8(Bp + 1 * 16 * K + ks * 32);
    bf16x8 b2 = ld8(Bp + 2 * 16 * K + ks * 32);
    bf16x8 b3 = ld8(Bp + 3 * 16 * K + ks * 32);
    bf16x8 a0 = ld8(Ap + ks * 32);
    bf16x8 a1 = ld8(Ap + (long)16 * K + ks * 32);
    acc[0][0] = __builtin_amdgcn_mfma_f32_16x16x32_bf16(a0, b0, acc[0][0], 0, 0, 0);
    acc[0][1] = __builtin_amdgcn_mfma_f32_16x16x32_bf16(a0, b1, acc[0][1], 0, 0, 0);
    acc[0][2] = __builtin_amdgcn_mfma_f32_16x16x32_bf16(a0, b2, acc[0][2], 0, 0, 0);
    acc[0][3] = __builtin_amdgcn_mfma_f32_16x16x32_bf16(a0, b3, acc[0][3], 0, 0, 0);
    acc[1][0] = __builtin_amdgcn_mfma_f32_16x16x32_bf16(a1, b0, acc[1][0], 0, 0, 0);
    acc[1][1] = __builtin_amdgcn_mfma_f32_16x16x32_bf16(a1, b1, acc[1][1], 0, 0, 0);
    acc[1][2] = __builtin_amdgcn_mfma_f32_16x16x32_bf16(a1, b2, acc[1][2], 0, 0, 0);
    acc[1][3] = __builtin_amdgcn_mfma_f32_16x16x32_bf16(a1, b3, acc[1][3], 0, 0, 0);
  }
#pragma unroll
  for (int mt = 0; mt < 2; mt++) {
#pragma unroll
    for (int rgi = 0; rgi < 4; rgi++) {
      int row = rowBase + mt * 16 + kg * 4 + rgi;
      int t = (EPI == 1) ? win_row_to_token(row) : row;
#pragma unroll
      for (int j = 0; j < 4; j++) {
        int col = colBase + j * 16 + m;
        float v = acc[mt][j][rgi] + bias[col];
        if (EPI == 0) {
          ((unsigned short*)out)[(long)row * 384 + col] = f2bf(v);
        } else {
          ((float*)out)[(long)t * 128 + col] = res[(long)t * 128 + col] + v;
        }
      }
    }
  }
}

// ---------- MFMA window attention (round-3 verbatim, passing) ----------
__global__ __launch_bounds__(256) void attn_mfma(const unsigned short* __restrict__ qkv,
                                                 const float* __restrict__ cls2,
                                                 unsigned short* __restrict__ out) {
  __shared__ unsigned short vt[128 * 64];       // V^T [d][m], zero-padded m>=49
  __shared__ unsigned short pb[4][64 * 64];     // P per head, rows n, cols m
  int win = blockIdx.x;
  int tid = threadIdx.x;
  const unsigned short* qbase = qkv + (long)win * 49 * 384;

  for (int i = tid; i < 49 * 128; i += 256) {
    int mm = i >> 7, d = i & 127;
    vt[d * 64 + (mm ^ ((d & 7) << 3))] = qbase[mm * 384 + 256 + d];
  }
  for (int i = tid; i < 128 * 15; i += 256) {   // zero pad rows m=49..63
    int d = i / 15, mm = 49 + i % 15;
    vt[d * 64 + (mm ^ ((d & 7) << 3))] = 0;
  }

  int h = tid >> 6, lane = tid & 63;
  int lr = lane & 15, g = lane >> 4;
  int w2 = win & 63;
  int cl = (((w2 >> 3) == 7) ? 2 : 0) + (((w2 & 7) == 7) ? 1 : 0);

  bf16x8 aq[4], bk[4];
  bf16x8 zf = {};
#pragma unroll
  for (int rt = 0; rt < 4; rt++)
    aq[rt] = ld8(qbase + (rt * 16 + lr) * 384 + h * 32 + g * 8);
#pragma unroll
  for (int ct = 0; ct < 4; ct++) {
    int mm = ct * 16 + lr;
    bk[ct] = (mm < 49) ? ld8(qbase + mm * 384 + 128 + h * 32 + g * 8) : zf;
  }
  f32x4 acc[4][4] = {};
#pragma unroll
  for (int rt = 0; rt < 4; rt++)
#pragma unroll
    for (int ct = 0; ct < 4; ct++)
      acc[rt][ct] = __builtin_amdgcn_mfma_f32_16x16x32_bf16(aq[rt], bk[ct], acc[rt][ct], 0, 0, 0);

  const float scale = 0.17677669529663687f;     // 32^-0.5
  const float* cb = cls2 + (long)(cl * 4 + h) * 16 * 256;
  unsigned short* P = pb[h];
#pragma unroll
  for (int rt = 0; rt < 4; rt++) {
    f32x4 c[4];
#pragma unroll
    for (int ct = 0; ct < 4; ct++)
      c[ct] = *reinterpret_cast<const f32x4*>(cb + (rt * 4 + ct) * 256 + lane * 4);
#pragma unroll
    for (int reg = 0; reg < 4; reg++) {
      float s0 = acc[rt][0][reg] * scale + c[0][reg];
      float s1 = acc[rt][1][reg] * scale + c[1][reg];
      float s2 = acc[rt][2][reg] * scale + c[2][reg];
      float s3 = acc[rt][3][reg] * scale + c[3][reg];
      float mx = fmaxf(fmaxf(s0, s1), fmaxf(s2, s3));
      mx = fmaxf(mx, __shfl_xor(mx, 1)); mx = fmaxf(mx, __shfl_xor(mx, 2));
      mx = fmaxf(mx, __shfl_xor(mx, 4)); mx = fmaxf(mx, __shfl_xor(mx, 8));
      float p0 = __expf(s0 - mx), p1 = __expf(s1 - mx);
      float p2 = __expf(s2 - mx), p3 = __expf(s3 - mx);
      float sum = p0 + p1 + p2 + p3;
      sum += __shfl_xor(sum, 1); sum += __shfl_xor(sum, 2);
      sum += __shfl_xor(sum, 4); sum += __shfl_xor(sum, 8);
      float inv = 1.f / sum;
      int n = rt * 16 + g * 4 + reg;
      int sw = (n & 7) << 3, rowb = n * 64;
      P[rowb + ((0 * 16 + lr) ^ sw)] = f2bf(p0 * inv);
      P[rowb + ((1 * 16 + lr) ^ sw)] = f2bf(p1 * inv);
      P[rowb + ((2 * 16 + lr) ^ sw)] = f2bf(p2 * inv);
      P[rowb + ((3 * 16 + lr) ^ sw)] = f2bf(p3 * inv);
    }
  }
  __syncthreads();   // vt ready (P is wave-private)

  f32x4 o[4][2] = {};
  bf16x8 bv[2][2];
#pragma unroll
  for (int dt = 0; dt < 2; dt++)
#pragma unroll
    for (int ks = 0; ks < 2; ks++) {
      int d = h * 32 + dt * 16 + lr;
      bv[dt][ks] = ld8(&vt[d * 64 + ((ks * 32 + g * 8) ^ ((d & 7) << 3))]);
    }
#pragma unroll
  for (int rt = 0; rt < 4; rt++)
#pragma unroll
    for (int ks = 0; ks < 2; ks++) {
      int n = rt * 16 + lr;
      bf16x8 ap = ld8(&P[n * 64 + ((ks * 32 + g * 8) ^ ((n & 7) << 3))]);
#pragma unroll
      for (int dt = 0; dt < 2; dt++)
        o[rt][dt] = __builtin_amdgcn_mfma_f32_16x16x32_bf16(ap, bv[dt][ks], o[rt][dt], 0, 0, 0);
    }
#pragma unroll
  for (int rt = 0; rt < 4; rt++)
#pragma unroll
    for (int dt = 0; dt < 2; dt++)
#pragma unroll
      for (int reg = 0; reg < 4; reg++) {
        int n = rt * 16 + g * 4 + reg;
        if (n < 49)
          out[((long)win * 49 + n) * 128 + h * 32 + dt * 16 + lr] = f2bf(o[rt][dt][reg]);
      }
}

// ---------- wave-local fused MLP: LN2 + MLP1 + GELU + MLP2 + residual ----------
// ZERO LDS, ZERO barriers. One wave = 16 tokens, fully independent.
// Swapped-operand trick: mfma(a,b) -> D[rows from a][cols from b], cols = lane&15.
//   D1 = mfma(w1_frag, token_frag) -> D1[w1col][token]: token = lr (lane-local!).
//   gelu in registers; repack C-layout -> B-frag via 4-lane-group shuffles;
//   D2 = mfma(w2_frag, gelu_frag) -> D2[outcol][token].
__global__ __launch_bounds__(256) void mlp_wave(
    const float* __restrict__ out1,
    const unsigned short* __restrict__ w1t,   // [512][128]  (w1col, k)
    const float* __restrict__ b1,
    const unsigned short* __restrict__ w2t,   // [128][512]  (outcol, k)
    const float* __restrict__ b2,
    const float* __restrict__ ln2w,
    const float* __restrict__ ln2b,
    float* __restrict__ dout) {
  int tid = threadIdx.x, w = tid >> 6, lane = tid & 63, lr = lane & 15, g = lane >> 4;
  long tok0 = (long)blockIdx.x * 64 + w * 16;   // this wave's 16 tokens
  const float* xrow = out1 + (tok0 + lr) * 128;

  // ---- LN2 in registers: lane (lr,g) owns cols {ksi*32 + g*8 + j} of token lr ----
  float xv[32];
  float s = 0.f, s2 = 0.f;
#pragma unroll
  for (int ksi = 0; ksi < 4; ksi++) {
    f32x4 v0 = *(const f32x4*)(xrow + ksi * 32 + g * 8);
    f32x4 v1 = *(const f32x4*)(xrow + ksi * 32 + g * 8 + 4);
#pragma unroll
    for (int j = 0; j < 4; j++) {
      xv[ksi * 8 + j]     = v0[j];
      xv[ksi * 8 + 4 + j] = v1[j];
      s  += v0[j] + v1[j];
      s2 += v0[j] * v0[j] + v1[j] * v1[j];
    }
  }
  // reduce over the 4 lanes sharing lr (g = 0..3): xor 16, then 32
  s  += __shfl_xor(s, 16);  s  += __shfl_xor(s, 32);
  s2 += __shfl_xor(s2, 16); s2 += __shfl_xor(s2, 32);
  float mu  = s * (1.f / 128.f);
  float inv = rsqrtf(s2 * (1.f / 128.f) - mu * mu + EPS_LN);

  // build LN token B-frags: aln[ksi] element j = ln(token lr, col ksi*32+g*8+j)
  bf16x8 aln[4];
#pragma unroll
  for (int ksi = 0; ksi < 4; ksi++) {
    f32x4 w0 = *(const f32x4*)(ln2w + ksi * 32 + g * 8);
    f32x4 w1v = *(const f32x4*)(ln2w + ksi * 32 + g * 8 + 4);
    f32x4 c0 = *(const f32x4*)(ln2b + ksi * 32 + g * 8);
    f32x4 c1 = *(const f32x4*)(ln2b + ksi * 32 + g * 8 + 4);
    union { unsigned int u[4]; bf16x8 v; } U;
#pragma unroll
    for (int d = 0; d < 4; d++) {
      int j0 = 2 * d, j1 = 2 * d + 1;
      float wj0 = (j0 < 4) ? w0[j0] : w1v[j0 - 4];
      float wj1 = (j1 < 4) ? w0[j1] : w1v[j1 - 4];
      float bj0 = (j0 < 4) ? c0[j0] : c1[j0 - 4];
      float bj1 = (j1 < 4) ? c0[j1] : c1[j1 - 4];
      float e0 = (xv[ksi * 8 + j0] - mu) * inv * wj0 + bj0;
      float e1 = (xv[ksi * 8 + j1] - mu) * inv * wj1 + bj1;
      U.u[d] = ((unsigned int)f2bf(e1) << 16) | (unsigned int)f2bf(e0);
    }
    aln[ksi] = U.v;
  }

  // repack shuffle indices (compile-time-free, lane-dependent):
  //   target lane (lr,g) frag elem j needs gelu(k16 = (g&1)*8+j) of tile 2kb+(g>>1),
  //   held by source lanes (lr, 2(g&1)) [j<4] and (lr, 2(g&1)+1) [j>=4].
  int idx0 = lr + ((lane & 16) << 1);   // lr + 16*2*(g&1)
  int idx1 = idx0 + 16;
  bool hi = (lane & 32) != 0;           // g>>1 selects tile 2kb (+1)

  f32x4 d2[8] = {};                      // D2[outcol tile][.]: 128 outcols x 16 tokens
  for (int c = 0; c < 4; c++) {          // dff chunks of 128
    // ---- MLP1 for w1cols c*128 .. c*128+127 ----
    unsigned int pk[8][2];
#pragma unroll
    for (int rt = 0; rt < 8; rt++) {
      f32x4 d1 = {};
#pragma unroll
      for (int ksi = 0; ksi < 4; ksi++) {
        bf16x8 aw = ld8(w1t + (long)(c * 128 + rt * 16 + lr) * 128 + ksi * 32 + g * 8);
        d1 = __builtin_amdgcn_mfma_f32_16x16x32_bf16(aw, aln[ksi], d1, 0, 0, 0);
      }
      // D1 layout: w1col = c*128 + rt*16 + g*4 + reg, token = lr
      f32x4 bb = *(const f32x4*)(b1 + c * 128 + rt * 16 + g * 4);
      float ge[4];
#pragma unroll
      for (int r = 0; r < 4; r++) {
        float v = d1[r] + bb[r];
        float u = v * (1.0f + 0.044715f * v * v);
        ge[r] = v / (1.0f + __expf(-1.5957691216f * u));
      }
      pk[rt][0] = ((unsigned int)f2bf(ge[1]) << 16) | (unsigned int)f2bf(ge[0]);
      pk[rt][1] = ((unsigned int)f2bf(ge[3]) << 16) | (unsigned int)f2bf(ge[2]);
    }
    // ---- repack to B-frags + MLP2 accumulate ----
#pragma unroll
    for (int kb = 0; kb < 4; kb++) {
      unsigned int a0 = __shfl(pk[2 * kb][0], idx0);
      unsigned int a1 = __shfl(pk[2 * kb][1], idx0);
      unsigned int a2 = __shfl(pk[2 * kb][0], idx1);
      unsigned int a3 = __shfl(pk[2 * kb][1], idx1);
      unsigned int e0 = __shfl(pk[2 * kb + 1][0], idx0);
      unsigned int e1 = __shfl(pk[2 * kb + 1][1], idx0);
      unsigned int e2 = __shfl(pk[2 * kb + 1][0], idx1);
      unsigned int e3 = __shfl(pk[2 * kb + 1][1], idx1);
      union { unsigned int u[4]; bf16x8 v; } U;
      U.u[0] = hi ? e0 : a0;
      U.u[1] = hi ? e1 : a1;
      U.u[2] = hi ? e2 : a2;
      U.u[3] = hi ? e3 : a3;
      bf16x8 bg = U.v;                   // gelu[token=lr][k = c*128+kb*32+g*8+j]
#pragma unroll
      for (int ot = 0; ot < 8; ot++) {
        bf16x8 aw2 = ld8(w2t + (long)(ot * 16 + lr) * 512 + c * 128 + kb * 32 + g * 8);
        d2[ot] = __builtin_amdgcn_mfma_f32_16x16x32_bf16(aw2, bg, d2[ot], 0, 0, 0);
      }
    }
  }

  // ---- epilogue: D2[outcol = ot*16+g*4+reg][token = lr]; coalesced f32x4 ----
#pragma unroll
  for (int ot = 0; ot < 8; ot++) {
    f32x4 res = *(const f32x4*)(out1 + (tok0 + lr) * 128 + ot * 16 + g * 4);
    f32x4 bb2 = *(const f32x4*)(b2 + ot * 16 + g * 4);
    f32x4 o;
#pragma unroll
    for (int r = 0; r < 4; r++) o[r] = res[r] + bb2[r] + d2[ot][r];
    *(f32x4*)(dout + (tok0 + lr) * 128 + ot * 16 + g * 4) = o;
  }
}

// ---------- launch ----------
extern "C" void kernel_launch(void* const* d_in, const int* in_sizes, int n_in,
                              void* d_out, int out_size, void* d_ws, size_t ws_size,
                              hipStream_t stream) {
  (void)in_sizes; (void)n_in; (void)out_size; (void)ws_size;
  const float* x      = (const float*)d_in[0];
  const float* qkv_w  = (const float*)d_in[1];
  const float* qkv_b  = (const float*)d_in[2];
  const float* proj_w = (const float*)d_in[3];
  const float* proj_b = (const float*)d_in[4];
  const float* rpb    = (const float*)d_in[5];
  const float* ln1_w  = (const float*)d_in[6];
  const float* ln1_b  = (const float*)d_in[7];
  const float* ln2_w  = (const float*)d_in[8];
  const float* ln2_b  = (const float*)d_in[9];
  const float* w1     = (const float*)d_in[10];
  const float* b1     = (const float*)d_in[11];
  const float* w2     = (const float*)d_in[12];
  const float* b2     = (const float*)d_in[13];

  char* ws = (char*)d_ws;
  // layout (round-3 offsets):
  //   0        : weights bf16 (393216)
  //   393216   : hb [T][128] bf16  -- aliased by attno
  //   26083328 : qkv [T][384] bf16
  //   103153664: out1 [T][128] f32
  //   154533888: cls2 (256 KB)
  unsigned short* wts   = (unsigned short*)ws;
  unsigned short* hb    = (unsigned short*)(ws + 393216);
  unsigned short* qkv   = (unsigned short*)(ws + 26083328);
  unsigned short* attno = hb;                      // alias: hb dead after QKV gemm
  float*          out1  = (float*)(ws + 103153664);
  float*          cls2  = (float*)(ws + 154533888);

  const int MP = T_TOK / 128;   // 784 m-panels

  prep_weights<<<768, 256, 0, stream>>>(qkv_w, proj_w, w1, w2, wts);
  prep_cls<<<256, 256, 0, stream>>>(rpb, cls2);
  ln_kernel<true><<<T_TOK / 4, 256, 0, stream>>>(x, ln1_w, ln1_b, hb);
  gemm_k<0, 4, 6><<<MP * 6, 256, 0, stream>>>(hb, wts, qkv_b, qkv, nullptr);
  attn_mfma<<<NWIN, 256, 0, stream>>>(qkv, cls2, attno);
  gemm_k<1, 4, 2><<<MP * 2, 256, 0, stream>>>(attno, wts + 49152, proj_b, out1, x);
  mlp_wave<<<T_TOK / 64, 256, 0, stream>>>(out1, wts + 65536, b1, wts + 131072, b2,
                                           ln2_w, ln2_b, (float*)d_out);
}